// Round 2
// baseline (82.256 us; speedup 1.0000x reference)
//
#include <hip/hip_runtime.h>

// Reference reduces exactly to mean(where(up < 0.2, up, 0)):
// the scatter-min writes strictly-positive values (110-i)/50, i<110, into a
// ZERO-initialized buffer -> min(0, pos) = 0 -> right2up == 0 identically,
// pixel_diff = |0 - up| = |up|, masked mean over all B*C*H*W elements.
// Only d_in[0] (up) is read; left/right are dead.
//
// Single fused kernel: block partials -> ws[], last-done block (atomic
// ticket, counter zeroed by a 4-byte hipMemsetAsync node each call) sums
// the 2048 partials in fixed index order -> deterministic output.

#define RED_BLOCKS 2048
#define RED_THREADS 256
#define NTHREADS_TOTAL (RED_BLOCKS * RED_THREADS)

__global__ __launch_bounds__(RED_THREADS)
void closs_fused_kernel(const float* __restrict__ up, float* __restrict__ out,
                        float* __restrict__ ws, unsigned int* __restrict__ counter,
                        int n4, float inv_n) {
    const float4* __restrict__ up4 = reinterpret_cast<const float4*>(up);
    const int tid = blockIdx.x * blockDim.x + threadIdx.x;

    float acc = 0.0f;
    if (n4 == 8 * NTHREADS_TOTAL) {
        // exact-fit fast path: 8 independent float4 loads in flight
        float a[8];
        #pragma unroll
        for (int k = 0; k < 8; ++k) {
            float4 v = up4[tid + k * NTHREADS_TOTAL];
            float ax = fabsf(v.x), ay = fabsf(v.y), az = fabsf(v.z), aw = fabsf(v.w);
            a[k]  = (ax < 0.2f) ? ax : 0.0f;
            a[k] += (ay < 0.2f) ? ay : 0.0f;
            a[k] += (az < 0.2f) ? az : 0.0f;
            a[k] += (aw < 0.2f) ? aw : 0.0f;
        }
        #pragma unroll
        for (int k = 0; k < 8; ++k) acc += a[k];
    } else {
        for (int idx = tid; idx < n4; idx += NTHREADS_TOTAL) {
            float4 v = up4[idx];
            float ax = fabsf(v.x), ay = fabsf(v.y), az = fabsf(v.z), aw = fabsf(v.w);
            acc += (ax < 0.2f) ? ax : 0.0f;
            acc += (ay < 0.2f) ? ay : 0.0f;
            acc += (az < 0.2f) ? az : 0.0f;
            acc += (aw < 0.2f) ? aw : 0.0f;
        }
    }

    // wave-64 reduce, then cross-wave via LDS
    #pragma unroll
    for (int off = 32; off > 0; off >>= 1) acc += __shfl_down(acc, off, 64);
    __shared__ float sdata[RED_THREADS / 64];
    const int lane = threadIdx.x & 63;
    const int wid  = threadIdx.x >> 6;
    if (lane == 0) sdata[wid] = acc;
    __syncthreads();

    __shared__ bool amLast;
    if (threadIdx.x == 0) {
        float s = sdata[0] + sdata[1] + sdata[2] + sdata[3];
        ws[blockIdx.x] = s;
        __threadfence();  // make partial visible device-scope before ticket
        unsigned int old = atomicAdd(counter, 1u);
        amLast = (old == (unsigned int)(gridDim.x - 1));
    }
    __syncthreads();

    if (amLast) {
        // fixed-order deterministic final reduce of RED_BLOCKS partials
        float facc = 0.0f;
        #pragma unroll
        for (int k = 0; k < RED_BLOCKS / RED_THREADS; ++k)
            facc += ws[threadIdx.x + k * RED_THREADS];
        #pragma unroll
        for (int off = 32; off > 0; off >>= 1) facc += __shfl_down(facc, off, 64);
        if (lane == 0) sdata[wid] = facc;
        __syncthreads();
        if (threadIdx.x == 0)
            out[0] = (sdata[0] + sdata[1] + sdata[2] + sdata[3]) * inv_n;
    }
}

extern "C" void kernel_launch(void* const* d_in, const int* in_sizes, int n_in,
                              void* d_out, int out_size, void* d_ws, size_t ws_size,
                              hipStream_t stream) {
    const float* up = (const float*)d_in[0];
    float* out = (float*)d_out;
    float* ws  = (float*)d_ws;                                  // RED_BLOCKS floats
    unsigned int* counter = (unsigned int*)((char*)d_ws + RED_BLOCKS * sizeof(float));

    const int n  = in_sizes[0];   // 64*1*512*512 = 16,777,216
    const int n4 = n >> 2;
    const float inv_n = 1.0f / (float)n;

    hipMemsetAsync(counter, 0, sizeof(unsigned int), stream);   // graph-capturable
    closs_fused_kernel<<<RED_BLOCKS, RED_THREADS, 0, stream>>>(up, out, ws, counter, n4, inv_n);
}

// Round 3
// 18.999 us; speedup vs baseline: 4.3296x; 4.3296x over previous
//
#include <hip/hip_runtime.h>

// Reference reduces exactly to mean(where(up < 0.2, up, 0)):
// the scatter-min writes strictly-positive values (110-i)/50, i<110, into a
// ZERO-initialized buffer -> min(0, pos) = 0 -> right2up == 0 identically,
// pixel_diff = |0 - up| = |up|, masked mean over all elements.
// Only d_in[0] (up) is read; left/right are dead.
//
// Two-kernel deterministic reduction. NO device-scope fence/atomic:
// round-2 post-mortem showed __threadfence()+atomic ticket per block costs
// ~100us on multi-XCD gfx950 (agent-scope release = L2 writeback class op).

#define RED_BLOCKS 2048
#define RED_THREADS 256
#define NT (RED_BLOCKS * RED_THREADS)   // 524,288 threads

__global__ __launch_bounds__(RED_THREADS)
void closs_partial_kernel(const float* __restrict__ up, float* __restrict__ ws, int n4) {
    const float4* __restrict__ up4 = reinterpret_cast<const float4*>(up);
    const int tid = blockIdx.x * blockDim.x + threadIdx.x;

    float a0 = 0.f, a1 = 0.f, a2 = 0.f, a3 = 0.f;

    if (n4 == 8 * NT) {
        // exact fit: 8 float4 per thread, processed as 2 groups of 4
        // INDEPENDENT in-flight loads (v[] materialized before any use).
        #pragma unroll
        for (int it = 0; it < 2; ++it) {
            float4 v0 = up4[tid + (it * 4 + 0) * NT];
            float4 v1 = up4[tid + (it * 4 + 1) * NT];
            float4 v2 = up4[tid + (it * 4 + 2) * NT];
            float4 v3 = up4[tid + (it * 4 + 3) * NT];
            {   float x = fabsf(v0.x), y = fabsf(v0.y), z = fabsf(v0.z), w = fabsf(v0.w);
                a0 += ((x < 0.2f) ? x : 0.f) + ((y < 0.2f) ? y : 0.f)
                    + ((z < 0.2f) ? z : 0.f) + ((w < 0.2f) ? w : 0.f); }
            {   float x = fabsf(v1.x), y = fabsf(v1.y), z = fabsf(v1.z), w = fabsf(v1.w);
                a1 += ((x < 0.2f) ? x : 0.f) + ((y < 0.2f) ? y : 0.f)
                    + ((z < 0.2f) ? z : 0.f) + ((w < 0.2f) ? w : 0.f); }
            {   float x = fabsf(v2.x), y = fabsf(v2.y), z = fabsf(v2.z), w = fabsf(v2.w);
                a2 += ((x < 0.2f) ? x : 0.f) + ((y < 0.2f) ? y : 0.f)
                    + ((z < 0.2f) ? z : 0.f) + ((w < 0.2f) ? w : 0.f); }
            {   float x = fabsf(v3.x), y = fabsf(v3.y), z = fabsf(v3.z), w = fabsf(v3.w);
                a3 += ((x < 0.2f) ? x : 0.f) + ((y < 0.2f) ? y : 0.f)
                    + ((z < 0.2f) ? z : 0.f) + ((w < 0.2f) ? w : 0.f); }
        }
    } else {
        for (int idx = tid; idx < n4; idx += NT) {
            float4 v = up4[idx];
            float x = fabsf(v.x), y = fabsf(v.y), z = fabsf(v.z), w = fabsf(v.w);
            a0 += ((x < 0.2f) ? x : 0.f) + ((y < 0.2f) ? y : 0.f)
                + ((z < 0.2f) ? z : 0.f) + ((w < 0.2f) ? w : 0.f);
        }
    }

    float acc = (a0 + a1) + (a2 + a3);

    #pragma unroll
    for (int off = 32; off > 0; off >>= 1) acc += __shfl_down(acc, off, 64);
    __shared__ float sdata[RED_THREADS / 64];
    const int lane = threadIdx.x & 63;
    const int wid  = threadIdx.x >> 6;
    if (lane == 0) sdata[wid] = acc;
    __syncthreads();
    if (threadIdx.x == 0)
        ws[blockIdx.x] = (sdata[0] + sdata[1]) + (sdata[2] + sdata[3]);
}

__global__ __launch_bounds__(RED_THREADS)
void closs_final_kernel(const float* __restrict__ ws, float* __restrict__ out,
                        float inv_n) {
    float acc = 0.0f;
    #pragma unroll
    for (int k = 0; k < RED_BLOCKS / RED_THREADS; ++k)
        acc += ws[threadIdx.x + k * RED_THREADS];
    #pragma unroll
    for (int off = 32; off > 0; off >>= 1) acc += __shfl_down(acc, off, 64);
    __shared__ float sdata[RED_THREADS / 64];
    const int lane = threadIdx.x & 63;
    const int wid  = threadIdx.x >> 6;
    if (lane == 0) sdata[wid] = acc;
    __syncthreads();
    if (threadIdx.x == 0)
        out[0] = ((sdata[0] + sdata[1]) + (sdata[2] + sdata[3])) * inv_n;
}

extern "C" void kernel_launch(void* const* d_in, const int* in_sizes, int n_in,
                              void* d_out, int out_size, void* d_ws, size_t ws_size,
                              hipStream_t stream) {
    const float* up = (const float*)d_in[0];
    float* out = (float*)d_out;
    float* ws  = (float*)d_ws;   // RED_BLOCKS floats = 8 KiB

    const int n  = in_sizes[0];  // 64*1*512*512 = 16,777,216
    const int n4 = n >> 2;
    const float inv_n = 1.0f / (float)n;

    closs_partial_kernel<<<RED_BLOCKS, RED_THREADS, 0, stream>>>(up, ws, n4);
    closs_final_kernel<<<1, RED_THREADS, 0, stream>>>(ws, out, inv_n);
}